// Round 9
// baseline (95.096 us; speedup 1.0000x reference)
//
#include <hip/hip_runtime.h>
#include <math.h>

#define BB 4
#define CC 64
#define HH 224
#define WW 224
#define HWW (HH*WW)
#define SS 257
#define CPB 8              // channels per pool block
#define NRC 16             // row chunks over 222 interior rows
#define RPC 14             // interior rows per chunk (last chunk: 12)
#define ENCW (3*BB*CC*SS)  // 197376 key words

typedef float f32x4 __attribute__((ext_vector_type(4)));
typedef int   i32x4 __attribute__((ext_vector_type(4)));

// Monotone float -> uint32 key (order-preserving), for integer atomicMax.
__device__ __forceinline__ unsigned fkey(float f) {
    unsigned u = __float_as_uint(f);
    return (u & 0x80000000u) ? ~u : (u | 0x80000000u);
}
__device__ __forceinline__ float funkey(unsigned k) {
    return (k & 0x80000000u) ? __uint_as_float(k & 0x7FFFFFFFu) : __uint_as_float(~k);
}
#define SENT 0x007FFFFFu  // fkey(-inf): empty-segment sentinel

// ---------------- init: enc keys -> SENT, nmax -> 0 ----------------
__global__ __launch_bounds__(256) void init_kernel(unsigned* __restrict__ enc,
                                                   int* __restrict__ nmax) {
    int i = blockIdx.x * 256 + threadIdx.x;
    if (i < ENCW / 4) ((uint4*)enc)[i] = make_uint4(SENT, SENT, SENT, SENT);
    if (i < 2 * BB) nmax[i] = 0;
}

// ---------------- segment-max pooling (+ folded nmax) ----------------
// grid (8 cgroups, 16 row-chunks, 12 zb) = 1536 blocks; block 256.
// R2..R7 post-mortems: hipcc sinks every VMEM load to its use (VGPR<=36
// always) -> per-wave MLP=1 -> ~900cyc x 9 serial latencies per iteration.
// Fix: inline-asm global_load_dwordx4 into two named register sets with
// counted s_waitcnt vmcnt(9) (never drain mid-loop). The waitcnt carries
// the batch registers as "+v" so consumers are data-dependent on it.
// NOTE: two-level macro indirection so SETA/SETB expand to 9 args (R8 fix).
#define SETA aF0,aF1,aF2,aF3,aF4,aF5,aF6,aF7,aL
#define SETB bF0,bF1,bF2,bF3,bF4,bF5,bF6,bF7,bL

#define ISSUE_(OFF, F0,F1,F2,F3,F4,F5,F6,F7,LL) \
    asm volatile( \
        "global_load_dwordx4 %0, %9, %10\n\t" \
        "global_load_dwordx4 %1, %9, %11\n\t" \
        "global_load_dwordx4 %2, %9, %12\n\t" \
        "global_load_dwordx4 %3, %9, %13\n\t" \
        "global_load_dwordx4 %4, %9, %14\n\t" \
        "global_load_dwordx4 %5, %9, %15\n\t" \
        "global_load_dwordx4 %6, %9, %16\n\t" \
        "global_load_dwordx4 %7, %9, %17\n\t" \
        "global_load_dwordx4 %8, %9, %18\n\t" \
        : "=&v"(F0), "=&v"(F1), "=&v"(F2), "=&v"(F3), \
          "=&v"(F4), "=&v"(F5), "=&v"(F6), "=&v"(F7), "=&v"(LL) \
        : "v"(OFF), "s"(q0), "s"(q1), "s"(q2), "s"(q3), \
          "s"(q4), "s"(q5), "s"(q6), "s"(q7), "s"(ql))
#define ISSUE(OFF, SET) ISSUE_(OFF, SET)

#define WAITB_(NSTR, F0,F1,F2,F3,F4,F5,F6,F7,LL) \
    asm volatile("s_waitcnt vmcnt(" NSTR ")" \
        : "+v"(F0), "+v"(F1), "+v"(F2), "+v"(F3), \
          "+v"(F4), "+v"(F5), "+v"(F6), "+v"(F7), "+v"(LL))
#define WAITB(NSTR, SET) WAITB_(NSTR, SET)

#define PR1(F, J, LX, LY, LZ, LW, MX, MW) do { \
    unsigned kx = fkey(F[0]), ky = fkey(F[1]), kz = fkey(F[2]), kw = fkey(F[3]); \
    unsigned* sg = seg + (J) * SS; \
    if ((MX) && kx > sg[LX]) atomicMax(&sg[LX], kx); \
    if (ky > sg[LY]) atomicMax(&sg[LY], ky); \
    if (kz > sg[LZ]) atomicMax(&sg[LZ], kz); \
    if ((MW) && kw > sg[LW]) atomicMax(&sg[LW], kw); \
} while (0)

#define PROCB_(IT, F0,F1,F2,F3,F4,F5,F6,F7,LL) do { \
    int gi = min((IT) * 256 + t, NGR - 1); \
    int g  = gi % 56; \
    bool mx = (g != 0), mw = (g != 55); \
    if (do_nmax) lmax = max(lmax, max(max(LL[0], LL[1]), max(LL[2], LL[3]))); \
    int lx = LL[0], ly = LL[1], lz = LL[2], lw = LL[3]; \
    PR1(F0, 0, lx, ly, lz, lw, mx, mw); \
    PR1(F1, 1, lx, ly, lz, lw, mx, mw); \
    PR1(F2, 2, lx, ly, lz, lw, mx, mw); \
    PR1(F3, 3, lx, ly, lz, lw, mx, mw); \
    PR1(F4, 4, lx, ly, lz, lw, mx, mw); \
    PR1(F5, 5, lx, ly, lz, lw, mx, mw); \
    PR1(F6, 6, lx, ly, lz, lw, mx, mw); \
    PR1(F7, 7, lx, ly, lz, lw, mx, mw); \
} while (0)
#define PROCB(IT, SET) PROCB_(IT, SET)

__global__ __launch_bounds__(256) void pool_kernel(
    const float* __restrict__ fT, const float* __restrict__ fR,
    const float* __restrict__ fV,
    const int* __restrict__ labT, const int* __restrict__ labR,
    unsigned* __restrict__ enc, int* __restrict__ nmax)
{
    __shared__ unsigned seg[CPB * SS];
    __shared__ int wmax[4];
    const int cg = blockIdx.x, rc = blockIdx.y;
    const int z = blockIdx.z >> 2, b = blockIdx.z & 3;
    const int t = threadIdx.x;
    const float* src = (z == 0) ? fT : (z == 1) ? fR : fV;
    const int*   lab = (z == 0) ? labT : labR;

    // wave-uniform plane bases as u64 -> SGPR pairs for the asm
    const float* pf = src + (size_t)(b * CC + cg * CPB) * HWW;
    const int*   lp = lab + (size_t)b * HWW;
    unsigned long long q0 = (unsigned long long)(uintptr_t)(pf + 0 * HWW);
    unsigned long long q1 = (unsigned long long)(uintptr_t)(pf + 1 * HWW);
    unsigned long long q2 = (unsigned long long)(uintptr_t)(pf + 2 * HWW);
    unsigned long long q3 = (unsigned long long)(uintptr_t)(pf + 3 * HWW);
    unsigned long long q4 = (unsigned long long)(uintptr_t)(pf + 4 * HWW);
    unsigned long long q5 = (unsigned long long)(uintptr_t)(pf + 5 * HWW);
    unsigned long long q6 = (unsigned long long)(uintptr_t)(pf + 6 * HWW);
    unsigned long long q7 = (unsigned long long)(uintptr_t)(pf + 7 * HWW);
    unsigned long long ql = (unsigned long long)(uintptr_t)lp;

    for (int i = t; i < CPB * SS; i += 256) seg[i] = SENT;

    const bool do_nmax = (cg == 0) && (z < 2);
    int lmax = -1;
    if (do_nmax && t < 112) {          // border rows 0 and 223 (full mask)
        const i32x4* l4 = (const i32x4*)lp;
        i32x4 v = (t < 56) ? l4[t] : l4[223 * 56 + (t - 56)];
        lmax = max(lmax, max(max(v[0], v[1]), max(v[2], v[3])));
    }
    __syncthreads();

    const int h0i = rc * RPC;                          // first interior row idx
    const int NGR = (min(222, h0i + RPC) - h0i) * 56;  // 784 (or 672 for rc=15)
    const unsigned base4 = (unsigned)((h0i + 1) * 56); // first image-row group

    f32x4 aF0, aF1, aF2, aF3, aF4, aF5, aF6, aF7; i32x4 aL;
    f32x4 bF0, bF1, bF2, bF3, bF4, bF5, bF6, bF7; i32x4 bL;

    unsigned vo0 = (base4 + (unsigned)min(0 * 256 + t, NGR - 1)) * 16u;
    unsigned vo1 = (base4 + (unsigned)min(1 * 256 + t, NGR - 1)) * 16u;
    unsigned vo2 = (base4 + (unsigned)min(2 * 256 + t, NGR - 1)) * 16u;
    unsigned vo3 = (base4 + (unsigned)min(3 * 256 + t, NGR - 1)) * 16u;

    ISSUE(vo0, SETA);
    ISSUE(vo1, SETB);  WAITB("9", SETA);
    PROCB(0, SETA);
    ISSUE(vo2, SETA);  WAITB("9", SETB);
    PROCB(1, SETB);
    ISSUE(vo3, SETB);  WAITB("9", SETA);
    PROCB(2, SETA);
    WAITB("0", SETB);
    PROCB(3, SETB);

    #pragma unroll
    for (int o = 32; o; o >>= 1) lmax = max(lmax, __shfl_xor(lmax, o, 64));
    if ((t & 63) == 0) wmax[t >> 6] = lmax;
    __syncthreads();   // orders seg[] for merge, wmax for reduce
    if (do_nmax && t == 0) {
        int m = max(max(wmax[0], wmax[1]), max(wmax[2], wmax[3]));
        atomicMax(&nmax[z * BB + b], m + 1);
    }

    // merge partial seg keys -> global enc keys
    unsigned* gp = enc + (size_t)((z * BB + b) * CC + cg * CPB) * SS;
    for (int i = t; i < CPB * SS; i += 256) {
        unsigned k = seg[i];
        if (k != SENT) atomicMax(&gp[i], k);
    }
}

// ---------------- chan_norm + W@x + b -> q/k/v in [3][B][S][C] ----------------
__global__ __launch_bounds__(512) void qkv_kernel(
    const unsigned* __restrict__ enc,
    const float* __restrict__ Wq, const float* __restrict__ bq,
    const float* __restrict__ Wk, const float* __restrict__ bk,
    const float* __restrict__ Wv, const float* __restrict__ bv,
    float* __restrict__ qkv)
{
    const int z = blockIdx.z, b = blockIdx.y;
    const int wid = threadIdx.x >> 6, lane = threadIdx.x & 63;
    const int n = blockIdx.x * 8 + wid;
    if (n >= SS) return;

    const float* Wm = (z == 0) ? Wq : (z == 1) ? Wk : Wv;
    const float* bm = (z == 0) ? bq : (z == 1) ? bk : bv;
    const unsigned* ep = enc + (size_t)((z * BB + b) * CC) * SS + n;

    unsigned kraw = ep[(size_t)lane * SS];
    float x = (kraw == SENT) ? 0.0f : funkey(kraw);   // empty segments -> 0
    if (z != 2) {  // chan_norm for q,k inputs
        float s = x;
        for (int o = 32; o; o >>= 1) s += __shfl_xor(s, o, 64);
        float xm = x - s * (1.0f / 64.0f);
        float s2 = xm * xm;
        for (int o = 32; o; o >>= 1) s2 += __shfl_xor(s2, o, 64);
        x = xm / (sqrtf(s2) + 1e-5f);
    }
    float acc = bm[lane];
    #pragma unroll
    for (int cI = 0; cI < 64; ++cI) {
        float xc = __shfl(x, cI, 64);
        acc = fmaf(Wm[lane * 64 + cI], xc, acc);
    }
    qkv[(size_t)((z * BB + b) * SS + n) * CC + lane] = acc;
}

// ---------------- attention row + PV ----------------
__global__ __launch_bounds__(256) void attn_kernel(
    const float* __restrict__ qkv, const int* __restrict__ nmax,
    float* __restrict__ wg)
{
    const int n = blockIdx.x, b = blockIdx.y, t = threadIdx.x;
    __shared__ float qs[CC];
    __shared__ float sim[512];
    __shared__ float red[256];
    __shared__ float pv[4][64];

    const int nT = nmax[b], nR = nmax[BB + b];
    float* wp = wg + (size_t)(b * SS + n) * CC;
    if (n >= nT) {                       // tmask zeroes this row
        if (t < CC) wp[t] = 0.0f;
        return;
    }
    const float* q = qkv + (size_t)(0 * BB + b) * SS * CC;
    const float* k = qkv + (size_t)(1 * BB + b) * SS * CC;
    const float* v = qkv + (size_t)(2 * BB + b) * SS * CC;

    if (t < CC) qs[t] = q[(size_t)n * CC + t];
    sim[t] = -INFINITY;
    sim[t + 256] = -INFINITY;
    __syncthreads();

    for (int m = t; m < SS; m += 256) {
        float s = -INFINITY;
        if (m < nR) {
            const float4* kr = (const float4*)(k + (size_t)m * CC);
            float acc = 0.0f;
            #pragma unroll
            for (int i = 0; i < 16; ++i) {
                float4 kv = kr[i];
                acc += qs[4*i+0]*kv.x + qs[4*i+1]*kv.y + qs[4*i+2]*kv.z + qs[4*i+3]*kv.w;
            }
            s = acc * 100.0f;            // /0.01 temperature
        }
        sim[m] = s;
    }
    __syncthreads();

    red[t] = fmaxf(sim[t], sim[t + 256]);
    __syncthreads();
    for (int s = 128; s > 0; s >>= 1) {
        if (t < s) red[t] = fmaxf(red[t], red[t + s]);
        __syncthreads();
    }
    const float mx = red[0];
    __syncthreads();

    float psum = 0.0f;
    for (int m = t; m < SS; m += 256) {
        float e = expf(sim[m] - mx);     // exp(-inf - mx) = 0 for masked cols
        sim[m] = e;
        psum += e;
    }
    red[t] = psum;
    __syncthreads();
    for (int s = 128; s > 0; s >>= 1) {
        if (t < s) red[t] += red[t + s];
        __syncthreads();
    }
    const float rdenom = 1.0f / red[0];

    const int g = t >> 6, c = t & 63;
    float acc = 0.0f;
    for (int m = g; m < SS; m += 4)
        acc = fmaf(sim[m], v[(size_t)m * CC + c], acc);
    pv[g][c] = acc;
    __syncthreads();
    if (t < CC)
        wp[t] = (pv[0][t] + pv[1][t] + pv[2][t] + pv[3][t]) * rdenom;
}

// ---------------- unpool gather ----------------
__global__ __launch_bounds__(256) void unpool_kernel(
    const float* __restrict__ wg, const int* __restrict__ labT,
    float* __restrict__ out)
{
    const int idx = blockIdx.x * 256 + threadIdx.x;  // over B*HW
    if (idx >= BB * HWW) return;
    const int b = idx / HWW, hw = idx - b * HWW;
    const int l = labT[idx];
    const float4* row = (const float4*)(wg + (size_t)(b * SS + l) * CC);
    float* op = out + (size_t)b * CC * HWW + hw;
    #pragma unroll
    for (int i = 0; i < 16; ++i) {
        float4 r = row[i];
        op[(size_t)(4*i+0) * HWW] = r.x;
        op[(size_t)(4*i+1) * HWW] = r.y;
        op[(size_t)(4*i+2) * HWW] = r.z;
        op[(size_t)(4*i+3) * HWW] = r.w;
    }
}

extern "C" void kernel_launch(void* const* d_in, const int* in_sizes, int n_in,
                              void* d_out, int out_size, void* d_ws, size_t ws_size,
                              hipStream_t stream) {
    (void)in_sizes; (void)n_in; (void)out_size; (void)ws_size;
    const float* fT  = (const float*)d_in[0];
    const float* fR  = (const float*)d_in[1];
    const float* fV  = (const float*)d_in[2];
    const float* Wq  = (const float*)d_in[3];
    const float* bq  = (const float*)d_in[4];
    const float* Wk  = (const float*)d_in[5];
    const float* bk  = (const float*)d_in[6];
    const float* Wv  = (const float*)d_in[7];
    const float* bv  = (const float*)d_in[8];
    const int* labT  = (const int*)d_in[9];
    const int* labR  = (const int*)d_in[10];
    float* out = (float*)d_out;

    unsigned* enc = (unsigned*)d_ws;              // [3][B][C][S] as keys
    float* qkv  = (float*)d_ws + ENCW;            // [3][B][S][C]
    float* wg   = qkv + 3 * BB * CC * SS;         // [B][S][C]
    int*   nmax = (int*)(wg + BB * CC * SS);      // [2][B]

    init_kernel<<<(ENCW / 4 + 255) / 256, 256, 0, stream>>>(enc, nmax);
    pool_kernel<<<dim3(CC / CPB, NRC, 12), 256, 0, stream>>>(fT, fR, fV, labT, labR, enc, nmax);
    qkv_kernel<<<dim3((SS + 7) / 8, BB, 3), 512, 0, stream>>>(enc, Wq, bq, Wk, bk, Wv, bv, qkv);
    attn_kernel<<<dim3(SS, BB), 256, 0, stream>>>(qkv, nmax, wg);
    unpool_kernel<<<(BB * HWW + 255) / 256, 256, 0, stream>>>(wg, labT, out);
}